// Round 4
// baseline (121.287 us; speedup 1.0000x reference)
//
#include <hip/hip_runtime.h>

// SparseConv1D on MI355X, round 11 — DIAGNOSTIC PROBE (intentional ~2x sconv).
// Evidence through R10: one 44.2us ws-poison fill per timed iteration (fill dispatch-id
// period 12) => sconv ~= 38-43us in EVERY structure tried, ~5x its 8.3us MFMA floor, and
// rocprof's top-5 cutoff (~44.9us) has always hidden sconv's counters. No resource model
// explains ~2700 stall cyc/tap/SIMD. This round measures instead of guessing:
//  - After the real tap loop, re-run an IDENTICAL steady-state tap engine (loadW/readB/
//    16 MFMA x32) into acc2, kept alive via junk*acc2 where junk=(float)(blockIdx.x>>30)
//    (always 0, unknowable at compile time -> DCE-proof; all acc indices static).
//  - Delta(dur_us) vs R10 = pure marginal tap-loop cost (no staging/epilogue pollution).
//  - If doubled sconv > ~45us it enters rocprof top-5 WITH MfmaUtil/VALUBusy/conflicts.
// Pre-committed: tap-loop-is-sink => dur ~120-127, sconv top-1 ~75-80us;
//                tap-loop-is-fine => dur ~97-103, mystery lives outside the loop.

#define B_    16
#define CIN   64
#define COUT  64
#define LEN   4096
#define NTAP  32

typedef float f32x4 __attribute__((ext_vector_type(4)));
typedef short bf16x8_s __attribute__((ext_vector_type(8)));
typedef __bf16 bf16x8_b __attribute__((ext_vector_type(8)));

template <typename V>
static __device__ inline auto mfma_16x16x32_bf16(V a, V b, f32x4 c, int)
    -> decltype(__builtin_amdgcn_mfma_f32_16x16x32_bf16(a, b, c, 0, 0, 0)) {
  return __builtin_amdgcn_mfma_f32_16x16x32_bf16(a, b, c, 0, 0, 0);
}
template <typename V>
static __device__ inline f32x4 mfma_16x16x32_bf16(V a, V b, f32x4 c, long) {
  return __builtin_amdgcn_mfma_f32_16x16x32_bf16(
      __builtin_bit_cast(bf16x8_b, a), __builtin_bit_cast(bf16x8_b, b), c, 0, 0, 0);
}

static __device__ inline unsigned short f32_to_bf16_rne(float f) {
  unsigned int u = __builtin_bit_cast(unsigned int, f);
  u += 0x7fffu + ((u >> 16) & 1u);
  return (unsigned short)(u >> 16);
}

// ---- prep_w: w[o][i][t] f32 -> Wf[t][c][m][lane][8] bf16 (frag-major, 8KB/tap) ----
__global__ __launch_bounds__(256) void prep_w(const float* __restrict__ w,
                                              unsigned short* __restrict__ wf) {
  const int base = blockIdx.x * 1024;          // grid 128 -> 131072 elems
#pragma unroll
  for (int it = 0; it < 4; ++it) {
    const int e = base + it * 256 + threadIdx.x;
    const int j = e & 7;
    const int lane = (e >> 3) & 63;
    const int m = (e >> 9) & 3;
    const int c = (e >> 11) & 1;
    const int t = e >> 12;
    const int o = m * 16 + (lane & 15);
    const int i = c * 32 + (lane >> 4) * 8 + j;
    wf[e] = f32_to_bf16_rne(w[(size_t)(o * CIN + i) * NTAP + t]);
  }
}

// ------- main: R10 structure + duplicated steady-state tap engine (probe) -------------
__global__ __launch_bounds__(512, 2) void sconv_main(const float* __restrict__ x,
                                                     const unsigned short* __restrict__ wf,
                                                     float* __restrict__ out) {
  constexpr int TAP[NTAP] = {-512, -256, -128, -96, -64, -48, -32, -24, -16, -12, -8,
                             -6,   -4,   -3,   -2,  -1,  0,   1,   2,   3,   4,  6,
                             8,    12,   16,   24,  32,  48,  64,  96,  128, 256};
  __shared__ alignas(16) char smem[131072];   // ring: 1024 rows x 128B, staged once (phased)

  const int id = blockIdx.x;                  // 256 blocks = 16 b x 16 l-tiles
  const int b = (id & 7) * 2 + (id >> 7);     // XCD k <- batches {2k,2k+1}
  const int l0 = ((id >> 3) & 15) * 256;      // 16 l-tiles of 256
  const int lb = l0 + 512;                    // ring-phase base (mult of 256)
  const int tid = threadIdx.x;
  const int wv = tid >> 6, lane = tid & 63;
  const int q = lane >> 4, r = lane & 15;
  const int lh = wv >> 1, ch = wv & 1;        // wave: l-quarter (64 l), i-half (32 i)

  const char* wbase = (const char*)wf;
  const float* xb = x + (size_t)b * CIN * LEN;

  auto stage_iter = [&](int lc) {
    const int h = lane & 7;
    const int i0 = 16 * (wv & 3) + 2 * h;
    const int row0 = lc + ((wv >> 2) << 5) + ((lane >> 3) << 2);
    const int gl = l0 + row0;                  // global l of the 4-quad (mult of 4)
    f32x4 va = {0.f, 0.f, 0.f, 0.f}, vb = {0.f, 0.f, 0.f, 0.f};
    if ((unsigned)gl < (unsigned)LEN) {
      va = *(const f32x4*)&xb[(size_t)i0 * LEN + gl];
      vb = *(const f32x4*)&xb[(size_t)(i0 + 1) * LEN + gl];
    }
#pragma unroll
    for (int j = 0; j < 4; ++j) {
      const unsigned u = (unsigned)f32_to_bf16_rne(va[j]) |
                         ((unsigned)f32_to_bf16_rne(vb[j]) << 16);
      const int slot = (lb + row0 + j) & 1023;
      const int cs = (i0 >> 3) ^ (slot & 7);
      *(unsigned*)(smem + slot * 128 + (cs << 4) + (i0 & 7) * 2) = u;
    }
  };

  bf16x8_s Wreg[2][4], Breg[2][4];
  f32x4 acc[4][4] = {};

  auto loadW = [&](int tt, int p) {            // global, frag-major, coalesced, L1-broadcast
    const char* src = wbase + tt * 8192 + ch * 4096 + lane * 16;
#pragma unroll
    for (int m = 0; m < 4; ++m)
      Wreg[p][m] = *(const bf16x8_s*)(src + m * 1024);
  };
  auto readB = [&](int tt, int p) {
    const int e = (TAP[tt] + r) & 7;
#pragma unroll
    for (int n = 0; n < 4; ++n) {
      const int slot = (lb + TAP[tt] + lh * 64 + 16 * n + r) & 1023;
      Breg[p][n] = *(const bf16x8_s*)(smem + slot * 128 + (((ch * 4 + q) ^ e) << 4));
    }
  };

  // ---- phase-1 stage: window rows [-512, 256) ----
  loadW(0, 0);
#pragma unroll 4
  for (int k = 0; k < 12; ++k) stage_iter(-512 + k * 64);
  __syncthreads();                             // phase-1 rows resident
  readB(0, 0);

  // ---- real tap loop (identical to R10) ----
#pragma unroll
  for (int t = 0; t < NTAP; ++t) {
    const int p = t & 1;
    if (t < 4) stage_iter(256 + t * 64);       // rows [256,512), hidden under MFMA
    if (t == 6) __syncthreads();               // phase-2 writes long issued
    if (t + 1 < NTAP) {
      loadW(t + 1, p ^ 1);                     // vmcnt-counted, 2-deep dbuf
      readB(t + 1, p ^ 1);                     // lgkmcnt-counted, 2-deep dbuf
    }
    __builtin_amdgcn_sched_barrier(0);
#pragma unroll
    for (int m = 0; m < 4; ++m)
#pragma unroll
      for (int n = 0; n < 4; ++n)
        acc[m][n] = mfma_16x16x32_bf16(Wreg[p][m], Breg[p][n], acc[m][n], 0);
  }

  // ---- PROBE PASS: identical steady-state tap engine into acc2 (no staging, no barriers).
  // Delta(dur) vs R10 == pure tap-loop marginal cost; acc2 kept alive via junk (==0).
  f32x4 acc2[4][4] = {};
  loadW(0, 0);
  readB(0, 0);
#pragma unroll
  for (int t = 0; t < NTAP; ++t) {
    const int p = t & 1;
    if (t + 1 < NTAP) {
      loadW(t + 1, p ^ 1);
      readB(t + 1, p ^ 1);
    }
    __builtin_amdgcn_sched_barrier(0);
#pragma unroll
    for (int m = 0; m < 4; ++m)
#pragma unroll
      for (int n = 0; n < 4; ++n)
        acc2[m][n] = mfma_16x16x32_bf16(Wreg[p][m], Breg[p][n], acc2[m][n], 0);
  }
  const float junk = (float)(int)(blockIdx.x >> 30);  // always 0; unknowable at compile time

  // ---- reduce the two i-halves through LDS (ring is dead now) ----
  __syncthreads();
  if (ch == 1) {
#pragma unroll
    for (int m = 0; m < 4; ++m)
#pragma unroll
      for (int n = 0; n < 4; ++n) {
        const f32x4 s = acc[m][n] + junk * acc2[m][n];
        *(f32x4*)(smem + lh * 16384 + ((m * 4 + n) * 64 + lane) * 16) = s;
      }
  }
  __syncthreads();
  if (ch == 0) {
#pragma unroll
    for (int m = 0; m < 4; ++m)
#pragma unroll
      for (int n = 0; n < 4; ++n) {
        const f32x4 other = *(const f32x4*)(smem + lh * 16384 + ((m * 4 + n) * 64 + lane) * 16);
        const f32x4 v = acc[m][n] + junk * acc2[m][n] + other;
        // C/D layout (verified): col(l) = lane&15, row(o) = (lane>>4)*4 + reg
#pragma unroll
        for (int d = 0; d < 4; ++d) {
          const int o = 16 * m + 4 * q + d;
          const int l = l0 + lh * 64 + 16 * n + r;
          out[((size_t)b * COUT + o) * LEN + l] = v[d];
        }
      }
  }
}

extern "C" void kernel_launch(void* const* d_in, const int* in_sizes, int n_in,
                              void* d_out, int out_size, void* d_ws, size_t ws_size,
                              hipStream_t stream) {
  const float* x = (const float*)d_in[0];        // [16][64][4096]
  const float* w = (const float*)d_in[1];        // [64][64][32]
  float* out = (float*)d_out;                    // [16][64][4096]

  unsigned short* wfp = (unsigned short*)d_ws;   // 256 KB frag-major W

  prep_w<<<dim3(128), 256, 0, stream>>>(w, wfp);
  sconv_main<<<dim3(256), 512, 0, stream>>>(x, wfp, out);
}

// Round 5
// 94.551 us; speedup vs baseline: 1.2828x; 1.2828x over previous
//
#include <hip/hip_runtime.h>

// SparseConv1D on MI355X, round 12.
// out[b,o,l] = sum_{t,i} W[o,i,t] * x[b,i,l+tap_t] = 32 shifted GEMMs (MFMA 16x16x32 bf16).
// R12 vs R11-probe findings: single-pass sconv ~= 30us; bank conflicts ~0; occupancy the
// standout (1 block/CU x 8 waves = 2/SIMD, MfmaUtil ~21%) => latency-bound: 1-tap prefetch
// (~78 cyc sibling cover) vs ~200-250cyc W L2 latency. R11's marginal was spill-polluted
// (acc+acc2=128 VGPR -> 60MB scratch) - probe deleted, and the fix AVOIDS spill by design:
//  - 1024 threads = 16 waves = 4 waves/SIMD (50% occ cap): waves = 8 l-eighths x 2 i-halves,
//    acc[4][2] = 32 VGPR/wave (halved). VGPR budget ~110 < 128 cap at 4 waves/SIMD.
//  - Per-wave stall now covered by 3 siblings' MFMA issue instead of 1.
//  - Ring (128KB, XOR-involution swizzle), W frag-major global->reg dbuf, counted-wait
//    tap loop, phased stage: all structurally unchanged from R10.

#define B_    16
#define CIN   64
#define COUT  64
#define LEN   4096
#define NTAP  32

typedef float f32x4 __attribute__((ext_vector_type(4)));
typedef short bf16x8_s __attribute__((ext_vector_type(8)));
typedef __bf16 bf16x8_b __attribute__((ext_vector_type(8)));

template <typename V>
static __device__ inline auto mfma_16x16x32_bf16(V a, V b, f32x4 c, int)
    -> decltype(__builtin_amdgcn_mfma_f32_16x16x32_bf16(a, b, c, 0, 0, 0)) {
  return __builtin_amdgcn_mfma_f32_16x16x32_bf16(a, b, c, 0, 0, 0);
}
template <typename V>
static __device__ inline f32x4 mfma_16x16x32_bf16(V a, V b, f32x4 c, long) {
  return __builtin_amdgcn_mfma_f32_16x16x32_bf16(
      __builtin_bit_cast(bf16x8_b, a), __builtin_bit_cast(bf16x8_b, b), c, 0, 0, 0);
}

static __device__ inline unsigned short f32_to_bf16_rne(float f) {
  unsigned int u = __builtin_bit_cast(unsigned int, f);
  u += 0x7fffu + ((u >> 16) & 1u);
  return (unsigned short)(u >> 16);
}

// ---- prep_w: w[o][i][t] f32 -> Wf[t][c][m][lane][8] bf16 (frag-major, 8KB/tap) ----
__global__ __launch_bounds__(256) void prep_w(const float* __restrict__ w,
                                              unsigned short* __restrict__ wf) {
  const int base = blockIdx.x * 1024;          // grid 128 -> 131072 elems
#pragma unroll
  for (int it = 0; it < 4; ++it) {
    const int e = base + it * 256 + threadIdx.x;
    const int j = e & 7;
    const int lane = (e >> 3) & 63;
    const int m = (e >> 9) & 3;
    const int c = (e >> 11) & 1;
    const int t = e >> 12;
    const int o = m * 16 + (lane & 15);
    const int i = c * 32 + (lane >> 4) * 8 + j;
    wf[e] = f32_to_bf16_rne(w[(size_t)(o * CIN + i) * NTAP + t]);
  }
}

// ------- main: 16 waves (4/SIMD), fused f32 staging into 128KB ring, counted-wait loop ----
__global__ __launch_bounds__(1024, 1) void sconv_main(const float* __restrict__ x,
                                                      const unsigned short* __restrict__ wf,
                                                      float* __restrict__ out) {
  constexpr int TAP[NTAP] = {-512, -256, -128, -96, -64, -48, -32, -24, -16, -12, -8,
                             -6,   -4,   -3,   -2,  -1,  0,   1,   2,   3,   4,  6,
                             8,    12,   16,   24,  32,  48,  64,  96,  128, 256};
  __shared__ alignas(16) char smem[131072];   // ring: 1024 rows x 128B, staged once (phased)

  const int id = blockIdx.x;                  // 256 blocks = 16 b x 16 l-tiles
  const int b = (id & 7) * 2 + (id >> 7);     // XCD k <- batches {2k,2k+1}
  const int l0 = ((id >> 3) & 15) * 256;      // 16 l-tiles of 256
  const int lb = l0 + 512;                    // ring-phase base (mult of 256)
  const int tid = threadIdx.x;
  const int wv = tid >> 6, lane = tid & 63;
  const int q = lane >> 4, r = lane & 15;
  const int lh = wv >> 1, ch = wv & 1;        // wave: l-eighth (32 l), i-half (32 i)

  const char* wbase = (const char*)wf;
  const float* xb = x + (size_t)b * CIN * LEN;

  // stage one [128 l][64 i] chunk at window rows [lc, lc+128): f32 -> bf16 -> swizzled ring.
  // lane map: h=lane&7 -> i0=16*(wv&3)+2h ; row0 = lc + ((wv>>2)&3)*32 + (lane>>3)*4.
  // write swizzle = readB's involution: chunk' = (i0>>3) ^ (slot&7).
  auto stage_iter = [&](int lc) {
    const int h = lane & 7;
    const int i0 = 16 * (wv & 3) + 2 * h;
    const int row0 = lc + (((wv >> 2) & 3) << 5) + ((lane >> 3) << 2);
    const int gl = l0 + row0;                  // global l of the 4-quad (mult of 4)
    f32x4 va = {0.f, 0.f, 0.f, 0.f}, vb = {0.f, 0.f, 0.f, 0.f};
    if ((unsigned)gl < (unsigned)LEN) {
      va = *(const f32x4*)&xb[(size_t)i0 * LEN + gl];
      vb = *(const f32x4*)&xb[(size_t)(i0 + 1) * LEN + gl];
    }
#pragma unroll
    for (int j = 0; j < 4; ++j) {
      const unsigned u = (unsigned)f32_to_bf16_rne(va[j]) |
                         ((unsigned)f32_to_bf16_rne(vb[j]) << 16);
      const int slot = (lb + row0 + j) & 1023;
      const int cs = (i0 >> 3) ^ (slot & 7);
      *(unsigned*)(smem + slot * 128 + (cs << 4) + (i0 & 7) * 2) = u;
    }
  };

  bf16x8_s Wreg[2][4], Breg[2][2];
  f32x4 acc[4][2] = {};

  auto loadW = [&](int tt, int p) {            // global, frag-major, coalesced, L1-broadcast
    const char* src = wbase + tt * 8192 + ch * 4096 + lane * 16;
#pragma unroll
    for (int m = 0; m < 4; ++m)
      Wreg[p][m] = *(const bf16x8_s*)(src + m * 1024);
  };
  // slot&7 == (TAP+r)&7 (lb, lh*32, 16n all 0 mod 8) -> same involution as the write side
  auto readB = [&](int tt, int p) {
    const int e = (TAP[tt] + r) & 7;
#pragma unroll
    for (int n = 0; n < 2; ++n) {
      const int slot = (lb + TAP[tt] + lh * 32 + 16 * n + r) & 1023;
      Breg[p][n] = *(const bf16x8_s*)(smem + slot * 128 + (((ch * 4 + q) ^ e) << 4));
    }
  };

  // ---- phase-1 stage: window rows [-512, 256) = 6 chunks of 128 ----
  loadW(0, 0);
#pragma unroll
  for (int k = 0; k < 6; ++k) stage_iter(-512 + k * 128);
  __syncthreads();                             // phase-1 rows resident
  readB(0, 0);

  // ---- tap loop: phase-2 stage (rows [256,512)) spread over t=0..1; barrier at t==6
  // ---- (first consumer of row>=256 is tap 17, prefetched at t==16) ----
#pragma unroll
  for (int t = 0; t < NTAP; ++t) {
    const int p = t & 1;
    if (t < 2) stage_iter(256 + t * 128);      // hidden under MFMA
    if (t == 6) __syncthreads();               // cheap: phase-2 writes long issued
    if (t + 1 < NTAP) {
      loadW(t + 1, p ^ 1);                     // vmcnt-counted, 2-deep dbuf
      readB(t + 1, p ^ 1);                     // lgkmcnt-counted, 2-deep dbuf
    }
    __builtin_amdgcn_sched_barrier(0);         // pin prefetch issue above this tap's MFMAs
#pragma unroll
    for (int m = 0; m < 4; ++m)
#pragma unroll
      for (int n = 0; n < 2; ++n)
        acc[m][n] = mfma_16x16x32_bf16(Wreg[p][m], Breg[p][n], acc[m][n], 0);
  }

  // ---- reduce the two i-halves through LDS (ring is dead now) ----
  __syncthreads();
  if (ch == 1) {
#pragma unroll
    for (int m = 0; m < 4; ++m)
#pragma unroll
      for (int n = 0; n < 2; ++n)
        *(f32x4*)(smem + lh * 8192 + ((m * 2 + n) * 64 + lane) * 16) = acc[m][n];
  }
  __syncthreads();
  if (ch == 0) {
#pragma unroll
    for (int m = 0; m < 4; ++m)
#pragma unroll
      for (int n = 0; n < 2; ++n) {
        const f32x4 other = *(const f32x4*)(smem + lh * 8192 + ((m * 2 + n) * 64 + lane) * 16);
        const f32x4 v = acc[m][n] + other;
        // C/D layout (verified): col(l) = lane&15, row(o) = (lane>>4)*4 + reg
#pragma unroll
        for (int d = 0; d < 4; ++d) {
          const int o = 16 * m + 4 * q + d;
          const int l = l0 + lh * 32 + 16 * n + r;
          out[((size_t)b * COUT + o) * LEN + l] = v[d];
        }
      }
  }
}

extern "C" void kernel_launch(void* const* d_in, const int* in_sizes, int n_in,
                              void* d_out, int out_size, void* d_ws, size_t ws_size,
                              hipStream_t stream) {
  const float* x = (const float*)d_in[0];        // [16][64][4096]
  const float* w = (const float*)d_in[1];        // [64][64][32]
  float* out = (float*)d_out;                    // [16][64][4096]

  unsigned short* wfp = (unsigned short*)d_ws;   // 256 KB frag-major W

  prep_w<<<dim3(128), 256, 0, stream>>>(w, wfp);
  sconv_main<<<dim3(256), 1024, 0, stream>>>(x, wfp, out);
}

// Round 6
// 89.315 us; speedup vs baseline: 1.3580x; 1.0586x over previous
//
#include <hip/hip_runtime.h>

// SparseConv1D on MI355X, round 13.
// out[b,o,l] = sum_{t,i} W[o,i,t] * x[b,i,l+tap_t] = 32 shifted GEMMs (MFMA 16x16x32 bf16).
// R13 vs R12 (R12's 16 waves REGRESSED 89.4->94.6: doubling waves halves per-wave MFMA work
// -> per-SIMD latency cover invariant; and 2x W ingestion/CU. Pipe model for R10: W 32KB/tap
// through L1 ~512cyc > B 384cyc LDS > MFMA 155cyc/SIMD; measured ~2250cyc/tap => unhidden W
// latency: 8 waves self-synchronize, all wait on L2 with only a 1-tap-deep W buffer):
//  - W prefetch depth 4 (Wreg[4][4], issue loadW(t+3) at tap t): counted vmcnt(12) gives
//    each wave a 2-3-tap (>=1000cyc) latency lead. No slot overlap (t+3)&3 != t&3.
//  - Full 1024-row window staged in PROLOGUE (16 stage_iters); tap loop is now pure
//    {loadW, readB, 16 MFMA} — zero barriers, zero staging inside.
//  - B stays 2-deep (LDS latency ~120cyc << tap). 8 waves / 1 block/CU / swizzle unchanged.
//  - VGPR ~210 < 256 @ 2 waves/SIMD — no spill by design (R11 lesson).

#define B_    16
#define CIN   64
#define COUT  64
#define LEN   4096
#define NTAP  32

typedef float f32x4 __attribute__((ext_vector_type(4)));
typedef short bf16x8_s __attribute__((ext_vector_type(8)));
typedef __bf16 bf16x8_b __attribute__((ext_vector_type(8)));

template <typename V>
static __device__ inline auto mfma_16x16x32_bf16(V a, V b, f32x4 c, int)
    -> decltype(__builtin_amdgcn_mfma_f32_16x16x32_bf16(a, b, c, 0, 0, 0)) {
  return __builtin_amdgcn_mfma_f32_16x16x32_bf16(a, b, c, 0, 0, 0);
}
template <typename V>
static __device__ inline f32x4 mfma_16x16x32_bf16(V a, V b, f32x4 c, long) {
  return __builtin_amdgcn_mfma_f32_16x16x32_bf16(
      __builtin_bit_cast(bf16x8_b, a), __builtin_bit_cast(bf16x8_b, b), c, 0, 0, 0);
}

static __device__ inline unsigned short f32_to_bf16_rne(float f) {
  unsigned int u = __builtin_bit_cast(unsigned int, f);
  u += 0x7fffu + ((u >> 16) & 1u);
  return (unsigned short)(u >> 16);
}

// ---- prep_w: w[o][i][t] f32 -> Wf[t][c][m][lane][8] bf16 (frag-major, 8KB/tap) ----
__global__ __launch_bounds__(256) void prep_w(const float* __restrict__ w,
                                              unsigned short* __restrict__ wf) {
  const int base = blockIdx.x * 1024;          // grid 128 -> 131072 elems
#pragma unroll
  for (int it = 0; it < 4; ++it) {
    const int e = base + it * 256 + threadIdx.x;
    const int j = e & 7;
    const int lane = (e >> 3) & 63;
    const int m = (e >> 9) & 3;
    const int c = (e >> 11) & 1;
    const int t = e >> 12;
    const int o = m * 16 + (lane & 15);
    const int i = c * 32 + (lane >> 4) * 8 + j;
    wf[e] = f32_to_bf16_rne(w[(size_t)(o * CIN + i) * NTAP + t]);
  }
}

// ------- main: 8 waves, full-prestage ring, pure tap loop, W depth-4 prefetch -----------
__global__ __launch_bounds__(512, 2) void sconv_main(const float* __restrict__ x,
                                                     const unsigned short* __restrict__ wf,
                                                     float* __restrict__ out) {
  constexpr int TAP[NTAP] = {-512, -256, -128, -96, -64, -48, -32, -24, -16, -12, -8,
                             -6,   -4,   -3,   -2,  -1,  0,   1,   2,   3,   4,  6,
                             8,    12,   16,   24,  32,  48,  64,  96,  128, 256};
  __shared__ alignas(16) char smem[131072];   // 1024 rows x 128B, staged ONCE in prologue

  const int id = blockIdx.x;                  // 256 blocks = 16 b x 16 l-tiles
  const int b = (id & 7) * 2 + (id >> 7);     // XCD k <- batches {2k,2k+1}
  const int l0 = ((id >> 3) & 15) * 256;      // 16 l-tiles of 256
  const int lb = l0 + 512;                    // ring-phase base (mult of 256)
  const int tid = threadIdx.x;
  const int wv = tid >> 6, lane = tid & 63;
  const int q = lane >> 4, r = lane & 15;
  const int lh = wv >> 1, ch = wv & 1;        // wave: l-quarter (64 l), i-half (32 i)

  const char* wbase = (const char*)wf;
  const float* xb = x + (size_t)b * CIN * LEN;

  // stage one [64 l][64 i] chunk at window rows [lc, lc+64): f32 -> bf16 -> swizzled ring.
  // lane map: h=lane&7 -> i0=16*(wv&3)+2h ; row0 = lc + (wv>>2)*32 + (lane>>3)*4.
  // write swizzle = readB's involution: chunk' = (i0>>3) ^ (slot&7).
  auto stage_iter = [&](int lc) {
    const int h = lane & 7;
    const int i0 = 16 * (wv & 3) + 2 * h;
    const int row0 = lc + ((wv >> 2) << 5) + ((lane >> 3) << 2);
    const int gl = l0 + row0;                  // global l of the 4-quad (mult of 4)
    f32x4 va = {0.f, 0.f, 0.f, 0.f}, vb = {0.f, 0.f, 0.f, 0.f};
    if ((unsigned)gl < (unsigned)LEN) {
      va = *(const f32x4*)&xb[(size_t)i0 * LEN + gl];
      vb = *(const f32x4*)&xb[(size_t)(i0 + 1) * LEN + gl];
    }
#pragma unroll
    for (int j = 0; j < 4; ++j) {
      const unsigned u = (unsigned)f32_to_bf16_rne(va[j]) |
                         ((unsigned)f32_to_bf16_rne(vb[j]) << 16);
      const int slot = (lb + row0 + j) & 1023;
      const int cs = (i0 >> 3) ^ (slot & 7);
      *(unsigned*)(smem + slot * 128 + (cs << 4) + (i0 & 7) * 2) = u;
    }
  };

  bf16x8_s Wreg[4][4], Breg[2][4];
  f32x4 acc[4][4] = {};

  auto loadW = [&](int tt, int p) {            // global, frag-major, coalesced, L1-broadcast
    const char* src = wbase + tt * 8192 + ch * 4096 + lane * 16;
#pragma unroll
    for (int m = 0; m < 4; ++m)
      Wreg[p][m] = *(const bf16x8_s*)(src + m * 1024);
  };
  // slot&7 == (TAP+r)&7 (lb, lh*64, 16n all 0 mod 8) -> same involution as the write side
  auto readB = [&](int tt, int p) {
    const int e = (TAP[tt] + r) & 7;
#pragma unroll
    for (int n = 0; n < 4; ++n) {
      const int slot = (lb + TAP[tt] + lh * 64 + 16 * n + r) & 1023;
      Breg[p][n] = *(const bf16x8_s*)(smem + slot * 128 + (((ch * 4 + q) ^ e) << 4));
    }
  };

  // ---- prologue: W pipeline primed 3 taps deep; FULL window rows [-512, 512) staged ----
  loadW(0, 0);
  loadW(1, 1);
  loadW(2, 2);
#pragma unroll 4
  for (int k = 0; k < 16; ++k) stage_iter(-512 + k * 64);
  __syncthreads();                             // the ONLY pre-epilogue barrier
  readB(0, 0);

  // ---- pure tap loop: no barriers, no staging; counted vmcnt(12)/lgkmcnt waits ----
#pragma unroll
  for (int t = 0; t < NTAP; ++t) {
    if (t + 3 < NTAP) loadW(t + 3, (t + 3) & 3);  // 3-tap W lead, slot-disjoint from t&3
    if (t + 1 < NTAP) readB(t + 1, (t + 1) & 1);  // 1-tap B lead (LDS ~120cyc)
    __builtin_amdgcn_sched_barrier(0);            // pin prefetch issue above this tap's MFMAs
#pragma unroll
    for (int m = 0; m < 4; ++m)
#pragma unroll
      for (int n = 0; n < 4; ++n)
        acc[m][n] = mfma_16x16x32_bf16(Wreg[t & 3][m], Breg[t & 1][n], acc[m][n], 0);
  }

  // ---- reduce the two i-halves through LDS (ring is dead now) ----
  __syncthreads();
  if (ch == 1) {
#pragma unroll
    for (int m = 0; m < 4; ++m)
#pragma unroll
      for (int n = 0; n < 4; ++n)
        *(f32x4*)(smem + lh * 16384 + ((m * 4 + n) * 64 + lane) * 16) = acc[m][n];
  }
  __syncthreads();
  if (ch == 0) {
#pragma unroll
    for (int m = 0; m < 4; ++m)
#pragma unroll
      for (int n = 0; n < 4; ++n) {
        const f32x4 other = *(const f32x4*)(smem + lh * 16384 + ((m * 4 + n) * 64 + lane) * 16);
        const f32x4 v = acc[m][n] + other;
        // C/D layout (verified): col(l) = lane&15, row(o) = (lane>>4)*4 + reg
#pragma unroll
        for (int d = 0; d < 4; ++d) {
          const int o = 16 * m + 4 * q + d;
          const int l = l0 + lh * 64 + 16 * n + r;
          out[((size_t)b * COUT + o) * LEN + l] = v[d];
        }
      }
  }
}

extern "C" void kernel_launch(void* const* d_in, const int* in_sizes, int n_in,
                              void* d_out, int out_size, void* d_ws, size_t ws_size,
                              hipStream_t stream) {
  const float* x = (const float*)d_in[0];        // [16][64][4096]
  const float* w = (const float*)d_in[1];        // [64][64][32]
  float* out = (float*)d_out;                    // [16][64][4096]

  unsigned short* wfp = (unsigned short*)d_ws;   // 256 KB frag-major W

  prep_w<<<dim3(128), 256, 0, stream>>>(w, wfp);
  sconv_main<<<dim3(256), 512, 0, stream>>>(x, wfp, out);
}